// Round 9
// baseline (211.162 us; speedup 1.0000x reference)
//
#include <hip/hip_runtime.h>
#include <hip/hip_bf16.h>
#include <math.h>

#define LRELU(v) ((v) > 0.f ? (v) : 0.2f * (v))

typedef __attribute__((ext_vector_type(8))) short bf16x8;
typedef __attribute__((ext_vector_type(4))) float f32x4;

__device__ inline unsigned int f2bf(float f) {
  unsigned int u = __float_as_uint(f);
  return (u + 0x7fffu + ((u >> 16) & 1u)) >> 16;   // RNE
}

// ---- W1 transpose + bf16 convert: wt[c*128+k] = bf16(W1[k*128+c]) ---------
__global__ __launch_bounds__(256) void wtrans_k(const float* __restrict__ W,
                                                unsigned short* __restrict__ wt)
{
  int idx = blockIdx.x * 256 + threadIdx.x;   // 16384 elements
  int k = idx >> 7, c = idx & 127;
  wt[c * 128 + k] = (unsigned short)f2bf(W[idx]);
}

// ---- GEMM1 (MFMA bf16): h1 = x @ W1, fused a_s1/a_d1, h1 stored bf16 ------
#define LDA 152
__global__ __launch_bounds__(256) void gemm1_k(
    const float* __restrict__ x, const unsigned short* __restrict__ wt,
    const float* __restrict__ atts, const float* __restrict__ attd,
    unsigned short* __restrict__ h1s, float* __restrict__ as1,
    float* __restrict__ ad1, int N)
{
  __shared__ unsigned short xs[64 * LDA];
  const int t = threadIdx.x;
  const int row0 = blockIdx.x * 64;
  const int lane = t & 63, w = t >> 6;

#pragma unroll
  for (int i = 0; i < 8; ++i) {
    int idx = t + i * 256;
    int r = idx >> 5, kq = idx & 31;
    int rr = row0 + r;
    float4 v = make_float4(0.f, 0.f, 0.f, 0.f);
    if (rr < N) v = *reinterpret_cast<const float4*>(&x[(size_t)rr * 128 + kq * 4]);
    unsigned int p0 = f2bf(v.x) | (f2bf(v.y) << 16);
    unsigned int p1 = f2bf(v.z) | (f2bf(v.w) << 16);
    *reinterpret_cast<uint2*>(&xs[r * LDA + kq * 4]) = make_uint2(p0, p1);
  }
  __syncthreads();

  const int l16 = lane & 15, lhi = lane >> 4;
  const int nb0 = w * 32;
  f32x4 acc[4][2];
#pragma unroll
  for (int m = 0; m < 4; ++m)
#pragma unroll
    for (int n = 0; n < 2; ++n) acc[m][n] = (f32x4){0.f, 0.f, 0.f, 0.f};

#pragma unroll
  for (int ks = 0; ks < 4; ++ks) {
    bf16x8 bf[2];
#pragma unroll
    for (int n = 0; n < 2; ++n) {
      int col = nb0 + n * 16 + l16;
      bf[n] = *reinterpret_cast<const bf16x8*>(&wt[col * 128 + ks * 32 + 8 * lhi]);
    }
#pragma unroll
    for (int m = 0; m < 4; ++m) {
      bf16x8 af = *reinterpret_cast<const bf16x8*>(
          &xs[(m * 16 + l16) * LDA + ks * 32 + 8 * lhi]);
      acc[m][0] = __builtin_amdgcn_mfma_f32_16x16x32_bf16(af, bf[0], acc[m][0], 0, 0, 0);
      acc[m][1] = __builtin_amdgcn_mfma_f32_16x16x32_bf16(af, bf[1], acc[m][1], 0, 0, 0);
    }
  }

#pragma unroll
  for (int n = 0; n < 2; ++n) {
    int col = nb0 + n * 16 + l16;
    float av = atts[col], dv = attd[col];
    int head = w * 2 + n;
#pragma unroll
    for (int m = 0; m < 4; ++m) {
#pragma unroll
      for (int r = 0; r < 4; ++r) {
        int row = row0 + m * 16 + lhi * 4 + r;
        float v = acc[m][n][r];
        float s = v * av, d = v * dv;
        s += __shfl_xor(s, 1); s += __shfl_xor(s, 2);
        s += __shfl_xor(s, 4); s += __shfl_xor(s, 8);
        d += __shfl_xor(d, 1); d += __shfl_xor(d, 2);
        d += __shfl_xor(d, 4); d += __shfl_xor(d, 8);
        if (row < N) {
          h1s[(size_t)row * 128 + col] = (unsigned short)f2bf(v);
          if (l16 == 0) { as1[row * 8 + head] = s; ad1[row * 8 + head] = d; }
        }
      }
    }
  }
}

// ==== Binned CSR build =====================================================
#define NBUK_MAX 256

__global__ __launch_bounds__(256) void bhist_k(const int* __restrict__ ei,
                                               int E, int N,
                                               int* __restrict__ bcnt, int nbuk)
{
  __shared__ int h[NBUK_MAX];
  for (int i = threadIdx.x; i < nbuk; i += 256) h[i] = 0;
  __syncthreads();
  const int Etot = E + N;
  const int base = blockIdx.x * 4096;
#pragma unroll 4
  for (int i = threadIdx.x; i < 4096; i += 256) {
    int e = base + i;
    if (e < Etot) {
      int d = (e < E) ? ei[E + e] : (e - E);
      atomicAdd(&h[d >> 8], 1);
    }
  }
  __syncthreads();
  for (int i = threadIdx.x; i < nbuk; i += 256)
    if (h[i]) atomicAdd(&bcnt[i], h[i]);
}

__global__ __launch_bounds__(256) void bscan_k(const int* __restrict__ bcnt,
                                               int* __restrict__ bbase,
                                               int* __restrict__ bpos, int nbuk)
{
  __shared__ int wsum[4], wtot[4];
  const int t = threadIdx.x, lane = t & 63, w = t >> 6;
  int v = (t < nbuk) ? bcnt[t] : 0;
  int incl = v;
#pragma unroll
  for (int off = 1; off < 64; off <<= 1) {
    int y = __shfl_up(incl, off);
    if (lane >= off) incl += y;
  }
  if (lane == 63) wtot[w] = incl;
  __syncthreads();
  if (t == 0) {
    int a = wtot[0], b = wtot[1], c = wtot[2];
    wsum[0] = 0; wsum[1] = a; wsum[2] = a + b; wsum[3] = a + b + c;
  }
  __syncthreads();
  int ex = wsum[w] + incl - v;
  if (t < nbuk) { bbase[t] = ex; bpos[t] = ex; }
  if (t == nbuk - 1) bbase[nbuk] = ex + v;
}

__global__ __launch_bounds__(256) void bscat_k(const int* __restrict__ ei,
                                               int E, int N,
                                               int* __restrict__ bpos,
                                               unsigned int* __restrict__ stg,
                                               int nbuk)
{
  __shared__ int h[NBUK_MAX], gp[NBUK_MAX], cur[NBUK_MAX];
  for (int i = threadIdx.x; i < nbuk; i += 256) { h[i] = 0; cur[i] = 0; }
  __syncthreads();
  const int Etot = E + N;
  const int base = blockIdx.x * 4096;
  int s[16], d[16];
#pragma unroll
  for (int i = 0; i < 16; ++i) {
    int e = base + i * 256 + threadIdx.x;
    if (e < Etot) {
      if (e < E) { s[i] = ei[e]; d[i] = ei[E + e]; }
      else       { s[i] = d[i] = e - E; }
      atomicAdd(&h[d[i] >> 8], 1);
    } else d[i] = -1;
  }
  __syncthreads();
  for (int i = threadIdx.x; i < nbuk; i += 256)
    gp[i] = h[i] ? atomicAdd(&bpos[i], h[i]) : 0;
  __syncthreads();
#pragma unroll
  for (int i = 0; i < 16; ++i) {
    if (d[i] >= 0) {
      int b = d[i] >> 8;
      int r = atomicAdd(&cur[b], 1);
      stg[gp[b] + r] = ((unsigned int)s[i] << 8) | (unsigned int)(d[i] & 255);
    }
  }
}

#define CCAP 4992
__global__ __launch_bounds__(512) void csr_k(const unsigned int* __restrict__ stg,
                                             const int* __restrict__ bbase,
                                             int* __restrict__ rowptr,
                                             int* __restrict__ col,
                                             int N, int nbuk)
{
  __shared__ int nh[256], nb[257], cur[256], wsum[4];
  __shared__ int cstage[CCAP];
  const int b = blockIdx.x, t = threadIdx.x;
  const int n0 = b << 8;
  const int e0 = bbase[b], e1 = bbase[b + 1], cnt = e1 - e0;
  if (t < 256) { nh[t] = 0; cur[t] = 0; }
  __syncthreads();
  for (int i = t; i < cnt; i += 512)
    atomicAdd(&nh[stg[e0 + i] & 255u], 1);
  __syncthreads();
  if (t < 256) {
    const int lane = t & 63, w = t >> 6;
    int v = nh[t], incl = v;
#pragma unroll
    for (int off = 1; off < 64; off <<= 1) {
      int y = __shfl_up(incl, off);
      if (lane >= off) incl += y;
    }
    if (lane == 63) wsum[w] = incl;
    __syncthreads();
    if (t == 0) {
      int a = wsum[0], bb = wsum[1], c = wsum[2];
      wsum[0] = 0; wsum[1] = a; wsum[2] = a + bb; wsum[3] = a + bb + c;
    }
    __syncthreads();
    int ex = wsum[w] + incl - v;
    nb[t] = ex;
    if (t == 255) nb[256] = ex + v;
  } else {
    __syncthreads();
    __syncthreads();
  }
  __syncthreads();
  const int nnodes = min(256, N - n0);
  for (int i = t; i < nnodes; i += 512) rowptr[n0 + i] = e0 + nb[i];
  if (b == nbuk - 1 && t == 0) rowptr[N] = e1;
  for (int i = t; i < cnt; i += 512) {
    unsigned int sd = stg[e0 + i];
    int li = sd & 255u;
    int p = nb[li] + atomicAdd(&cur[li], 1);
    int sv = (int)(sd >> 8);
    if (p < CCAP) cstage[p] = sv; else col[e0 + p] = sv;
  }
  __syncthreads();
  const int lim = min(cnt, CCAP);
  for (int i = t; i < lim; i += 512) col[e0 + i] = cstage[i];
}

// ---- AGG1: 4 edges/wave-step, 16 lanes/edge, uint4 (8ch) per lane ---------
__global__ __launch_bounds__(256) void agg1_k(
    const unsigned int* __restrict__ h1b, const float* __restrict__ as1,
    const float* __restrict__ ad1, const int* __restrict__ rowptr,
    const int* __restrict__ col, const float* __restrict__ b1,
    const float* __restrict__ gamma, const float* __restrict__ beta,
    const float* __restrict__ mean, const float* __restrict__ var,
    float* __restrict__ hmid, int N)
{
  const int wid = threadIdx.x >> 6, lane = threadIdx.x & 63;
  const int n = blockIdx.x * 4 + wid;
  if (n >= N) return;
  const int el = lane >> 4;          // edge slot 0..3
  const int cl = lane & 15;          // channel block: ch cl*8 .. cl*8+7
  const int h  = cl >> 1;            // head of this channel block
  const float adv = ad1[n * 8 + h];
  float den = 0.f;
  float acc[8];
#pragma unroll
  for (int k = 0; k < 8; ++k) acc[k] = 0.f;
  const int jb = rowptr[n], je = rowptr[n + 1];
  for (int j = jb; j < je; j += 8) {
    int j0 = j + el, j1 = j + 4 + el;
    bool v0 = j0 < je, v1 = j1 < je;
    int s0 = col[v0 ? j0 : je - 1];
    int s1 = col[v1 ? j1 : je - 1];
    float e0 = as1[s0 * 8 + h];
    float e1 = as1[s1 * 8 + h];
    uint4 u0 = *reinterpret_cast<const uint4*>(&h1b[(size_t)s0 * 64 + cl * 4]);
    uint4 u1 = *reinterpret_cast<const uint4*>(&h1b[(size_t)s1 * 64 + cl * 4]);
    float p0 = v0 ? __expf(LRELU(e0 + adv)) : 0.f;
    float p1 = v1 ? __expf(LRELU(e1 + adv)) : 0.f;
    den += p0 + p1;
    unsigned int w0[4] = {u0.x, u0.y, u0.z, u0.w};
    unsigned int w1[4] = {u1.x, u1.y, u1.z, u1.w};
#pragma unroll
    for (int k = 0; k < 4; ++k) {
      acc[2 * k]     += p0 * __uint_as_float(w0[k] << 16);
      acc[2 * k + 1] += p0 * __uint_as_float(w0[k] & 0xffff0000u);
      acc[2 * k]     += p1 * __uint_as_float(w1[k] << 16);
      acc[2 * k + 1] += p1 * __uint_as_float(w1[k] & 0xffff0000u);
    }
  }
  // combine across the 4 edge slots
  den += __shfl_xor(den, 16); den += __shfl_xor(den, 32);
#pragma unroll
  for (int k = 0; k < 8; ++k) {
    acc[k] += __shfl_xor(acc[k], 16);
    acc[k] += __shfl_xor(acc[k], 32);
  }
  if (el == 0) {
    float r = 1.f / (den + 1e-16f);
    int c0 = cl * 8;
    float o[8];
#pragma unroll
    for (int k = 0; k < 8; ++k) {
      int c = c0 + k;
      float ov = acc[k] * r + b1[c];
      float bn = (ov - mean[c]) * rsqrtf(var[c] + 1e-5f) * gamma[c] + beta[c];
      o[k] = bn > 0.f ? bn : expm1f(bn);
    }
    *reinterpret_cast<float4*>(&hmid[(size_t)n * 128 + c0]) =
        make_float4(o[0], o[1], o[2], o[3]);
    *reinterpret_cast<float4*>(&hmid[(size_t)n * 128 + c0 + 4]) =
        make_float4(o[4], o[5], o[6], o[7]);
  }
}

// ---- GEMM2: h2p = hmid @ W2 (128->40) f32, fused a_s2/a_d2 ----------------
__global__ __launch_bounds__(256) void gemm2_k(
    const float* __restrict__ hmid, const float* __restrict__ W2,
    const float* __restrict__ atts, const float* __restrict__ attd,
    float* __restrict__ h2p, float* __restrict__ as2, float* __restrict__ ad2,
    int N)
{
  __shared__ float hm[128 * 36];
  __shared__ float w2t[40 * 36];
  const int t = threadIdx.x;
  const int n0 = blockIdx.x * 128;
  const int lane = t & 63, w = t >> 6;
  const int ng = lane >> 3, cg = lane & 7;
  const int nloc = w * 32 + ng * 4;

  float acc[4][5];
#pragma unroll
  for (int i = 0; i < 4; ++i)
#pragma unroll
    for (int j = 0; j < 5; ++j) acc[i][j] = 0.f;

  for (int kc = 0; kc < 4; ++kc) {
    __syncthreads();
#pragma unroll
    for (int i = 0; i < 4; ++i) {
      int idx = t + i * 256;
      int r = idx >> 3, kq = idx & 7;
      int rr = n0 + r;
      float4 v = make_float4(0.f, 0.f, 0.f, 0.f);
      if (rr < N)
        v = *reinterpret_cast<const float4*>(&hmid[(size_t)rr * 128 + kc * 32 + kq * 4]);
      *reinterpret_cast<float4*>(&hm[r * 36 + kq * 4]) = v;
    }
#pragma unroll
    for (int i = 0; i < 5; ++i) {
      int flat = t + i * 256;
      int c = flat >> 5, kk = flat & 31;
      w2t[c * 36 + kk] = W2[(size_t)(kc * 32 + kk) * 40 + c];
    }
    __syncthreads();
#pragma unroll
    for (int k4 = 0; k4 < 8; ++k4) {
      float hv[4][4];
#pragma unroll
      for (int i = 0; i < 4; ++i)
        *reinterpret_cast<float4*>(hv[i]) =
            *reinterpret_cast<const float4*>(&hm[(nloc + i) * 36 + k4 * 4]);
      float wv[5][4];
#pragma unroll
      for (int j = 0; j < 5; ++j)
        *reinterpret_cast<float4*>(wv[j]) =
            *reinterpret_cast<const float4*>(&w2t[(cg * 5 + j) * 36 + k4 * 4]);
#pragma unroll
      for (int i = 0; i < 4; ++i)
#pragma unroll
        for (int j = 0; j < 5; ++j)
#pragma unroll
          for (int kk = 0; kk < 4; ++kk)
            acc[i][j] += hv[i][kk] * wv[j][kk];
    }
  }

  float asv[5], adv[5];
#pragma unroll
  for (int j = 0; j < 5; ++j) { asv[j] = atts[cg * 5 + j]; adv[j] = attd[cg * 5 + j]; }
#pragma unroll
  for (int i = 0; i < 4; ++i) {
    int n = n0 + nloc + i;
    if (n >= N) continue;
    float ps = 0.f, pd = 0.f;
#pragma unroll
    for (int j = 0; j < 5; ++j) { ps += acc[i][j] * asv[j]; pd += acc[i][j] * adv[j]; }
#pragma unroll
    for (int off = 1; off < 8; off <<= 1) {
      ps += __shfl_xor(ps, off);
      pd += __shfl_xor(pd, off);
    }
#pragma unroll
    for (int j = 0; j < 5; ++j) h2p[(size_t)n * 40 + cg * 5 + j] = acc[i][j];
    if (cg == 0) { as2[n] = ps; ad2[n] = pd; }
  }
}

// ---- AGG2: 3 edges/wave-step, 20 lanes/edge, float2 (2ch) per lane --------
__global__ __launch_bounds__(256) void agg2_k(
    const float* __restrict__ h2p, const float* __restrict__ as2,
    const float* __restrict__ ad2, const int* __restrict__ rowptr,
    const int* __restrict__ col, const float* __restrict__ b2,
    float* __restrict__ out, int N)
{
  const int wid = threadIdx.x >> 6, lane = threadIdx.x & 63;
  const int n = blockIdx.x * 4 + wid;
  if (n >= N) return;
  const int el = (lane >= 40) ? 2 : (lane >= 20 ? 1 : 0);
  const int cl = lane - el * 20;          // 0..19 (lanes 60-63: 20-23, unused)
  const int c0 = (cl < 20 ? cl : 19) * 2; // clamped channel pair base
  const bool lv = lane < 60;
  const float adv = ad2[n];
  float den = 0.f, a0 = 0.f, a1 = 0.f;
  const int jb = rowptr[n], je = rowptr[n + 1];
  for (int j = jb; j < je; j += 6) {
    int j0 = j + el, j1 = j + 3 + el;
    bool v0 = lv && (j0 < je), v1 = lv && (j1 < je);
    int s0 = col[v0 ? j0 : je - 1];
    int s1 = col[v1 ? j1 : je - 1];
    float e0 = as2[s0], e1 = as2[s1];
    float2 f0 = *reinterpret_cast<const float2*>(&h2p[(size_t)s0 * 40 + c0]);
    float2 f1 = *reinterpret_cast<const float2*>(&h2p[(size_t)s1 * 40 + c0]);
    float p0 = v0 ? __expf(LRELU(e0 + adv)) : 0.f;
    float p1 = v1 ? __expf(LRELU(e1 + adv)) : 0.f;
    den += p0 + p1;
    a0 += p0 * f0.x + p1 * f1.x;
    a1 += p0 * f0.y + p1 * f1.y;
  }
  // combine the 3 edge slots: den from lanes {0,20,40}; pair cl from {cl,cl+20,cl+40}
  float dt = __shfl(den, 0) + __shfl(den, 20) + __shfl(den, 40);
  int base = (lane < 20) ? lane : 0;
  float a0t = __shfl(a0, base) + __shfl(a0, base + 20) + __shfl(a0, base + 40);
  float a1t = __shfl(a1, base) + __shfl(a1, base + 20) + __shfl(a1, base + 40);
  const bool act = lane < 20;
  float r = 1.f / (dt + 1e-16f);
  float o0 = a0t * r + b2[c0];
  float o1 = a1t * r + b2[c0 + 1];
  // log_softmax over 40 values held as 20 lanes x 2 (reduce within lanes 0..31)
  float mv = act ? fmaxf(o0, o1) : -INFINITY;
#pragma unroll
  for (int off = 1; off < 32; off <<= 1) mv = fmaxf(mv, __shfl_xor(mv, off));
  float ex = act ? (__expf(o0 - mv) + __expf(o1 - mv)) : 0.f;
#pragma unroll
  for (int off = 1; off < 32; off <<= 1) ex += __shfl_xor(ex, off);
  float ls = logf(ex);
  if (act) {
    float2 ov = make_float2(o0 - mv - ls, o1 - mv - ls);
    *reinterpret_cast<float2*>(&out[(size_t)n * 40 + c0]) = ov;
  }
}

// ---------------------------------------------------------------------------
extern "C" void kernel_launch(void* const* d_in, const int* in_sizes, int n_in,
                              void* d_out, int out_size, void* d_ws,
                              size_t ws_size, hipStream_t stream)
{
  const float* x      = (const float*)d_in[0];
  const int*   ei     = (const int*)d_in[1];
  const float* W1     = (const float*)d_in[2];
  const float* att_s1 = (const float*)d_in[3];
  const float* att_d1 = (const float*)d_in[4];
  const float* b1     = (const float*)d_in[5];
  const float* gamma  = (const float*)d_in[6];
  const float* beta   = (const float*)d_in[7];
  const float* mean   = (const float*)d_in[8];
  const float* var    = (const float*)d_in[9];
  const float* W2     = (const float*)d_in[10];
  const float* att_s2 = (const float*)d_in[11];
  const float* att_d2 = (const float*)d_in[12];
  const float* b2     = (const float*)d_in[13];
  float* out = (float*)d_out;

  const int N = in_sizes[0] / 128;
  const int E = in_sizes[1] / 2;
  const int Etot = E + N;
  const int nbuk = (N + 255) >> 8;
  const int nchunk = (Etot + 4095) / 4096;

  char* ws = (char*)d_ws;
  size_t off = 0;
  auto alloc = [&](size_t bytes) -> void* {
    void* p = ws + off;
    off = (off + bytes + 255) & ~(size_t)255;
    return p;
  };
  unsigned short* h1s = (unsigned short*)alloc((size_t)N * 128 * 2);
  float* as1  = (float*)alloc((size_t)N * 8 * 4);
  float* ad1  = (float*)alloc((size_t)N * 8 * 4);
  float* hmid = (float*)alloc((size_t)N * 128 * 4);
  int* rowptr = (int*)alloc((size_t)(N + 1) * 4);
  int* col    = (int*)alloc((size_t)Etot * 4);
  unsigned int* stg = (unsigned int*)alloc((size_t)Etot * 4);
  int* bcnt   = (int*)alloc(NBUK_MAX * 4);
  int* bbase  = (int*)alloc((NBUK_MAX + 1) * 4);
  int* bpos   = (int*)alloc(NBUK_MAX * 4);
  unsigned short* wt = (unsigned short*)alloc(16384 * 2);
  // layer-2 reuses dead layer-1 buffers
  float* h2p = (float*)h1s;   // N*40*4 B <= N*128*2 B
  float* as2 = as1;
  float* ad2 = ad1;

  hipMemsetAsync(bcnt, 0, NBUK_MAX * 4, stream);

  wtrans_k<<<64, 256, 0, stream>>>(W1, wt);
  gemm1_k<<<(N + 63) / 64, 256, 0, stream>>>(x, wt, att_s1, att_d1,
                                             h1s, as1, ad1, N);
  bhist_k<<<nchunk, 256, 0, stream>>>(ei, E, N, bcnt, nbuk);
  bscan_k<<<1, 256, 0, stream>>>(bcnt, bbase, bpos, nbuk);
  bscat_k<<<nchunk, 256, 0, stream>>>(ei, E, N, bpos, stg, nbuk);
  csr_k<<<nbuk, 512, 0, stream>>>(stg, bbase, rowptr, col, N, nbuk);

  agg1_k<<<(N + 3) / 4, 256, 0, stream>>>((const unsigned int*)h1s, as1, ad1,
                                          rowptr, col, b1,
                                          gamma, beta, mean, var, hmid, N);
  gemm2_k<<<(N + 127) / 128, 256, 0, stream>>>(hmid, W2, att_s2, att_d2,
                                               h2p, as2, ad2, N);
  agg2_k<<<(N + 3) / 4, 256, 0, stream>>>(h2p, as2, ad2, rowptr, col, b2,
                                          out, N);
}

// Round 10
// 178.552 us; speedup vs baseline: 1.1826x; 1.1826x over previous
//
#include <hip/hip_runtime.h>
#include <hip/hip_bf16.h>
#include <math.h>

#define LRELU(v) ((v) > 0.f ? (v) : 0.2f * (v))

typedef __attribute__((ext_vector_type(8))) short bf16x8;
typedef __attribute__((ext_vector_type(4))) float f32x4;

__device__ inline unsigned int f2bf(float f) {
  unsigned int u = __float_as_uint(f);
  return (u + 0x7fffu + ((u >> 16) & 1u)) >> 16;   // RNE
}

// ---- W1 transpose + bf16 convert: wt[c*128+k] = bf16(W1[k*128+c]) ---------
__global__ __launch_bounds__(256) void wtrans_k(const float* __restrict__ W,
                                                unsigned short* __restrict__ wt)
{
  int idx = blockIdx.x * 256 + threadIdx.x;   // 16384 elements
  int k = idx >> 7, c = idx & 127;
  wt[c * 128 + k] = (unsigned short)f2bf(W[idx]);
}

// ---- GEMM1 (MFMA bf16): h1 = x @ W1, fused a_s1/a_d1, h1 stored bf16 ------
#define LDA 152
__global__ __launch_bounds__(256) void gemm1_k(
    const float* __restrict__ x, const unsigned short* __restrict__ wt,
    const float* __restrict__ atts, const float* __restrict__ attd,
    unsigned short* __restrict__ h1s, float* __restrict__ as1,
    float* __restrict__ ad1, int N)
{
  __shared__ unsigned short xs[64 * LDA];
  const int t = threadIdx.x;
  const int row0 = blockIdx.x * 64;
  const int lane = t & 63, w = t >> 6;

#pragma unroll
  for (int i = 0; i < 8; ++i) {
    int idx = t + i * 256;
    int r = idx >> 5, kq = idx & 31;
    int rr = row0 + r;
    float4 v = make_float4(0.f, 0.f, 0.f, 0.f);
    if (rr < N) v = *reinterpret_cast<const float4*>(&x[(size_t)rr * 128 + kq * 4]);
    unsigned int p0 = f2bf(v.x) | (f2bf(v.y) << 16);
    unsigned int p1 = f2bf(v.z) | (f2bf(v.w) << 16);
    *reinterpret_cast<uint2*>(&xs[r * LDA + kq * 4]) = make_uint2(p0, p1);
  }
  __syncthreads();

  const int l16 = lane & 15, lhi = lane >> 4;
  const int nb0 = w * 32;
  f32x4 acc[4][2];
#pragma unroll
  for (int m = 0; m < 4; ++m)
#pragma unroll
    for (int n = 0; n < 2; ++n) acc[m][n] = (f32x4){0.f, 0.f, 0.f, 0.f};

#pragma unroll
  for (int ks = 0; ks < 4; ++ks) {
    bf16x8 bf[2];
#pragma unroll
    for (int n = 0; n < 2; ++n) {
      int col = nb0 + n * 16 + l16;
      bf[n] = *reinterpret_cast<const bf16x8*>(&wt[col * 128 + ks * 32 + 8 * lhi]);
    }
#pragma unroll
    for (int m = 0; m < 4; ++m) {
      bf16x8 af = *reinterpret_cast<const bf16x8*>(
          &xs[(m * 16 + l16) * LDA + ks * 32 + 8 * lhi]);
      acc[m][0] = __builtin_amdgcn_mfma_f32_16x16x32_bf16(af, bf[0], acc[m][0], 0, 0, 0);
      acc[m][1] = __builtin_amdgcn_mfma_f32_16x16x32_bf16(af, bf[1], acc[m][1], 0, 0, 0);
    }
  }

#pragma unroll
  for (int n = 0; n < 2; ++n) {
    int col = nb0 + n * 16 + l16;
    float av = atts[col], dv = attd[col];
    int head = w * 2 + n;
#pragma unroll
    for (int m = 0; m < 4; ++m) {
#pragma unroll
      for (int r = 0; r < 4; ++r) {
        int row = row0 + m * 16 + lhi * 4 + r;
        float v = acc[m][n][r];
        float s = v * av, d = v * dv;
        s += __shfl_xor(s, 1); s += __shfl_xor(s, 2);
        s += __shfl_xor(s, 4); s += __shfl_xor(s, 8);
        d += __shfl_xor(d, 1); d += __shfl_xor(d, 2);
        d += __shfl_xor(d, 4); d += __shfl_xor(d, 8);
        if (row < N) {
          h1s[(size_t)row * 128 + col] = (unsigned short)f2bf(v);
          if (l16 == 0) { as1[row * 8 + head] = s; ad1[row * 8 + head] = d; }
        }
      }
    }
  }
}

// ==== Binned CSR build =====================================================
#define NBUK_MAX 256

__global__ __launch_bounds__(256) void bhist_k(const int* __restrict__ ei,
                                               int E, int N,
                                               int* __restrict__ bcnt, int nbuk)
{
  __shared__ int h[NBUK_MAX];
  for (int i = threadIdx.x; i < nbuk; i += 256) h[i] = 0;
  __syncthreads();
  const int Etot = E + N;
  const int base = blockIdx.x * 4096;
#pragma unroll 4
  for (int i = threadIdx.x; i < 4096; i += 256) {
    int e = base + i;
    if (e < Etot) {
      int d = (e < E) ? ei[E + e] : (e - E);
      atomicAdd(&h[d >> 8], 1);
    }
  }
  __syncthreads();
  for (int i = threadIdx.x; i < nbuk; i += 256)
    if (h[i]) atomicAdd(&bcnt[i], h[i]);
}

__global__ __launch_bounds__(256) void bscan_k(const int* __restrict__ bcnt,
                                               int* __restrict__ bbase,
                                               int* __restrict__ bpos, int nbuk)
{
  __shared__ int wsum[4], wtot[4];
  const int t = threadIdx.x, lane = t & 63, w = t >> 6;
  int v = (t < nbuk) ? bcnt[t] : 0;
  int incl = v;
#pragma unroll
  for (int off = 1; off < 64; off <<= 1) {
    int y = __shfl_up(incl, off);
    if (lane >= off) incl += y;
  }
  if (lane == 63) wtot[w] = incl;
  __syncthreads();
  if (t == 0) {
    int a = wtot[0], b = wtot[1], c = wtot[2];
    wsum[0] = 0; wsum[1] = a; wsum[2] = a + b; wsum[3] = a + b + c;
  }
  __syncthreads();
  int ex = wsum[w] + incl - v;
  if (t < nbuk) { bbase[t] = ex; bpos[t] = ex; }
  if (t == nbuk - 1) bbase[nbuk] = ex + v;
}

__global__ __launch_bounds__(256) void bscat_k(const int* __restrict__ ei,
                                               int E, int N,
                                               int* __restrict__ bpos,
                                               unsigned int* __restrict__ stg,
                                               int nbuk)
{
  __shared__ int h[NBUK_MAX], gp[NBUK_MAX], cur[NBUK_MAX];
  for (int i = threadIdx.x; i < nbuk; i += 256) { h[i] = 0; cur[i] = 0; }
  __syncthreads();
  const int Etot = E + N;
  const int base = blockIdx.x * 4096;
  int s[16], d[16];
#pragma unroll
  for (int i = 0; i < 16; ++i) {
    int e = base + i * 256 + threadIdx.x;
    if (e < Etot) {
      if (e < E) { s[i] = ei[e]; d[i] = ei[E + e]; }
      else       { s[i] = d[i] = e - E; }
      atomicAdd(&h[d[i] >> 8], 1);
    } else d[i] = -1;
  }
  __syncthreads();
  for (int i = threadIdx.x; i < nbuk; i += 256)
    gp[i] = h[i] ? atomicAdd(&bpos[i], h[i]) : 0;
  __syncthreads();
#pragma unroll
  for (int i = 0; i < 16; ++i) {
    if (d[i] >= 0) {
      int b = d[i] >> 8;
      int r = atomicAdd(&cur[b], 1);
      stg[gp[b] + r] = ((unsigned int)s[i] << 8) | (unsigned int)(d[i] & 255);
    }
  }
}

#define CCAP 4992
__global__ __launch_bounds__(512) void csr_k(const unsigned int* __restrict__ stg,
                                             const int* __restrict__ bbase,
                                             int* __restrict__ rowptr,
                                             int* __restrict__ col,
                                             int N, int nbuk)
{
  __shared__ int nh[256], nb[257], cur[256], wsum[4];
  __shared__ int cstage[CCAP];
  const int b = blockIdx.x, t = threadIdx.x;
  const int n0 = b << 8;
  const int e0 = bbase[b], e1 = bbase[b + 1], cnt = e1 - e0;
  if (t < 256) { nh[t] = 0; cur[t] = 0; }
  __syncthreads();
  for (int i = t; i < cnt; i += 512)
    atomicAdd(&nh[stg[e0 + i] & 255u], 1);
  __syncthreads();
  if (t < 256) {
    const int lane = t & 63, w = t >> 6;
    int v = nh[t], incl = v;
#pragma unroll
    for (int off = 1; off < 64; off <<= 1) {
      int y = __shfl_up(incl, off);
      if (lane >= off) incl += y;
    }
    if (lane == 63) wsum[w] = incl;
    __syncthreads();
    if (t == 0) {
      int a = wsum[0], bb = wsum[1], c = wsum[2];
      wsum[0] = 0; wsum[1] = a; wsum[2] = a + bb; wsum[3] = a + bb + c;
    }
    __syncthreads();
    int ex = wsum[w] + incl - v;
    nb[t] = ex;
    if (t == 255) nb[256] = ex + v;
  } else {
    __syncthreads();
    __syncthreads();
  }
  __syncthreads();
  const int nnodes = min(256, N - n0);
  for (int i = t; i < nnodes; i += 512) rowptr[n0 + i] = e0 + nb[i];
  if (b == nbuk - 1 && t == 0) rowptr[N] = e1;
  for (int i = t; i < cnt; i += 512) {
    unsigned int sd = stg[e0 + i];
    int li = sd & 255u;
    int p = nb[li] + atomicAdd(&cur[li], 1);
    int sv = (int)(sd >> 8);
    if (p < CCAP) cstage[p] = sv; else col[e0 + p] = sv;
  }
  __syncthreads();
  const int lim = min(cnt, CCAP);
  for (int i = t; i < lim; i += 512) col[e0 + i] = cstage[i];
}

// ---- AGG1: wave/node, no-max softmax, unroll-8, 32-bit addressing ---------
// lane owns channels {2*lane, 2*lane+1} (same head h=lane>>3)
__global__ __launch_bounds__(256) void agg1_k(
    const unsigned int* __restrict__ h1b, const float* __restrict__ as1,
    const float* __restrict__ ad1, const int* __restrict__ rowptr,
    const int* __restrict__ col, const float* __restrict__ b1,
    const float* __restrict__ gamma, const float* __restrict__ beta,
    const float* __restrict__ mean, const float* __restrict__ var,
    float* __restrict__ hmid, int N)
{
  const int wid = threadIdx.x >> 6, lane = threadIdx.x & 63;
  const int n = blockIdx.x * 4 + wid;
  if (n >= N) return;
  const int h = lane >> 3;
  const int c0 = lane * 2;
  const float adv = ad1[n * 8 + h];
  float den = 0.f, a0 = 0.f, a1 = 0.f;
  const int jb = rowptr[n], je = rowptr[n + 1];
  int j = jb;
  for (; j + 8 <= je; j += 8) {
    int s[8];
#pragma unroll
    for (int q = 0; q < 8; ++q) s[q] = col[j + q];
    float e[8];
#pragma unroll
    for (int q = 0; q < 8; ++q) e[q] = as1[s[q] * 8 + h];
    unsigned int u[8];
#pragma unroll
    for (int q = 0; q < 8; ++q) u[q] = h1b[s[q] * 64 + lane];
#pragma unroll
    for (int q = 0; q < 8; ++q) {
      float p = __expf(LRELU(e[q] + adv));
      den += p;
      a0 += p * __uint_as_float(u[q] << 16);
      a1 += p * __uint_as_float(u[q] & 0xffff0000u);
    }
  }
  for (; j < je; ++j) {
    int s = col[j];
    float e = LRELU(as1[s * 8 + h] + adv);
    unsigned int u = h1b[s * 64 + lane];
    float p = __expf(e);
    den += p;
    a0 += p * __uint_as_float(u << 16);
    a1 += p * __uint_as_float(u & 0xffff0000u);
  }
  float r = 1.f / (den + 1e-16f);
  float o0 = a0 * r + b1[c0];
  float o1 = a1 * r + b1[c0 + 1];
  float bn0 = (o0 - mean[c0]) * rsqrtf(var[c0] + 1e-5f) * gamma[c0] + beta[c0];
  float bn1 = (o1 - mean[c0 + 1]) * rsqrtf(var[c0 + 1] + 1e-5f) * gamma[c0 + 1] + beta[c0 + 1];
  float2 o;
  o.x = bn0 > 0.f ? bn0 : expm1f(bn0);
  o.y = bn1 > 0.f ? bn1 : expm1f(bn1);
  *reinterpret_cast<float2*>(&hmid[n * 128 + c0]) = o;
}

// ---- GEMM2: h2p = hmid @ W2 (128->40) f32, fused a_s2/a_d2 ----------------
__global__ __launch_bounds__(256) void gemm2_k(
    const float* __restrict__ hmid, const float* __restrict__ W2,
    const float* __restrict__ atts, const float* __restrict__ attd,
    float* __restrict__ h2p, float* __restrict__ as2, float* __restrict__ ad2,
    int N)
{
  __shared__ float hm[128 * 36];
  __shared__ float w2t[40 * 36];
  const int t = threadIdx.x;
  const int n0 = blockIdx.x * 128;
  const int lane = t & 63, w = t >> 6;
  const int ng = lane >> 3, cg = lane & 7;
  const int nloc = w * 32 + ng * 4;

  float acc[4][5];
#pragma unroll
  for (int i = 0; i < 4; ++i)
#pragma unroll
    for (int j = 0; j < 5; ++j) acc[i][j] = 0.f;

  for (int kc = 0; kc < 4; ++kc) {
    __syncthreads();
#pragma unroll
    for (int i = 0; i < 4; ++i) {
      int idx = t + i * 256;
      int r = idx >> 3, kq = idx & 7;
      int rr = n0 + r;
      float4 v = make_float4(0.f, 0.f, 0.f, 0.f);
      if (rr < N)
        v = *reinterpret_cast<const float4*>(&hmid[(size_t)rr * 128 + kc * 32 + kq * 4]);
      *reinterpret_cast<float4*>(&hm[r * 36 + kq * 4]) = v;
    }
#pragma unroll
    for (int i = 0; i < 5; ++i) {
      int flat = t + i * 256;
      int c = flat >> 5, kk = flat & 31;
      w2t[c * 36 + kk] = W2[(size_t)(kc * 32 + kk) * 40 + c];
    }
    __syncthreads();
#pragma unroll
    for (int k4 = 0; k4 < 8; ++k4) {
      float hv[4][4];
#pragma unroll
      for (int i = 0; i < 4; ++i)
        *reinterpret_cast<float4*>(hv[i]) =
            *reinterpret_cast<const float4*>(&hm[(nloc + i) * 36 + k4 * 4]);
      float wv[5][4];
#pragma unroll
      for (int j = 0; j < 5; ++j)
        *reinterpret_cast<float4*>(wv[j]) =
            *reinterpret_cast<const float4*>(&w2t[(cg * 5 + j) * 36 + k4 * 4]);
#pragma unroll
      for (int i = 0; i < 4; ++i)
#pragma unroll
        for (int j = 0; j < 5; ++j)
#pragma unroll
          for (int kk = 0; kk < 4; ++kk)
            acc[i][j] += hv[i][kk] * wv[j][kk];
    }
  }

  float asv[5], adv[5];
#pragma unroll
  for (int j = 0; j < 5; ++j) { asv[j] = atts[cg * 5 + j]; adv[j] = attd[cg * 5 + j]; }
#pragma unroll
  for (int i = 0; i < 4; ++i) {
    int n = n0 + nloc + i;
    if (n >= N) continue;
    float ps = 0.f, pd = 0.f;
#pragma unroll
    for (int j = 0; j < 5; ++j) { ps += acc[i][j] * asv[j]; pd += acc[i][j] * adv[j]; }
#pragma unroll
    for (int off = 1; off < 8; off <<= 1) {
      ps += __shfl_xor(ps, off);
      pd += __shfl_xor(pd, off);
    }
#pragma unroll
    for (int j = 0; j < 5; ++j) h2p[(size_t)n * 40 + cg * 5 + j] = acc[i][j];
    if (cg == 0) { as2[n] = ps; ad2[n] = pd; }
  }
}

// ---- AGG2: wave/node, no-max softmax, unroll-4, clamped lane, 32-bit ------
__global__ __launch_bounds__(256) void agg2_k(
    const float* __restrict__ h2p, const float* __restrict__ as2,
    const float* __restrict__ ad2, const int* __restrict__ rowptr,
    const int* __restrict__ col, const float* __restrict__ b2,
    float* __restrict__ out, int N)
{
  const int wid = threadIdx.x >> 6, lane = threadIdx.x & 63;
  const int n = blockIdx.x * 4 + wid;
  if (n >= N) return;
  const bool act = lane < 40;
  const int cl = act ? lane : 39;
  const float adv = ad2[n];
  float den = 0.f, acc = 0.f;
  const int jb = rowptr[n], je = rowptr[n + 1];
  int j = jb;
  for (; j + 4 <= je; j += 4) {
    int s0 = col[j], s1 = col[j + 1], s2 = col[j + 2], s3 = col[j + 3];
    float e0 = as2[s0], e1 = as2[s1], e2 = as2[s2], e3 = as2[s3];
    float v0 = h2p[s0 * 40 + cl];
    float v1 = h2p[s1 * 40 + cl];
    float v2 = h2p[s2 * 40 + cl];
    float v3 = h2p[s3 * 40 + cl];
    e0 = LRELU(e0 + adv); e1 = LRELU(e1 + adv);
    e2 = LRELU(e2 + adv); e3 = LRELU(e3 + adv);
    float p0 = __expf(e0), p1 = __expf(e1);
    float p2 = __expf(e2), p3 = __expf(e3);
    den += p0; den += p1; den += p2; den += p3;
    acc += p0 * v0; acc += p1 * v1; acc += p2 * v2; acc += p3 * v3;
  }
  for (; j < je; ++j) {
    int s = col[j];
    float e = LRELU(as2[s] + adv);
    float v = h2p[s * 40 + cl];
    float p = __expf(e);
    den += p;
    acc += p * v;
  }
  float o = acc / (den + 1e-16f) + b2[cl];
  float mv = act ? o : -INFINITY;
#pragma unroll
  for (int off = 1; off < 64; off <<= 1) mv = fmaxf(mv, __shfl_xor(mv, off));
  float ex = act ? __expf(o - mv) : 0.f;
#pragma unroll
  for (int off = 1; off < 64; off <<= 1) ex += __shfl_xor(ex, off);
  float ls = logf(ex);
  if (act) out[n * 40 + lane] = o - mv - ls;
}

// ---------------------------------------------------------------------------
extern "C" void kernel_launch(void* const* d_in, const int* in_sizes, int n_in,
                              void* d_out, int out_size, void* d_ws,
                              size_t ws_size, hipStream_t stream)
{
  const float* x      = (const float*)d_in[0];
  const int*   ei     = (const int*)d_in[1];
  const float* W1     = (const float*)d_in[2];
  const float* att_s1 = (const float*)d_in[3];
  const float* att_d1 = (const float*)d_in[4];
  const float* b1     = (const float*)d_in[5];
  const float* gamma  = (const float*)d_in[6];
  const float* beta   = (const float*)d_in[7];
  const float* mean   = (const float*)d_in[8];
  const float* var    = (const float*)d_in[9];
  const float* W2     = (const float*)d_in[10];
  const float* att_s2 = (const float*)d_in[11];
  const float* att_d2 = (const float*)d_in[12];
  const float* b2     = (const float*)d_in[13];
  float* out = (float*)d_out;

  const int N = in_sizes[0] / 128;
  const int E = in_sizes[1] / 2;
  const int Etot = E + N;
  const int nbuk = (N + 255) >> 8;
  const int nchunk = (Etot + 4095) / 4096;

  char* ws = (char*)d_ws;
  size_t off = 0;
  auto alloc = [&](size_t bytes) -> void* {
    void* p = ws + off;
    off = (off + bytes + 255) & ~(size_t)255;
    return p;
  };
  unsigned short* h1s = (unsigned short*)alloc((size_t)N * 128 * 2);
  float* as1  = (float*)alloc((size_t)N * 8 * 4);
  float* ad1  = (float*)alloc((size_t)N * 8 * 4);
  float* hmid = (float*)alloc((size_t)N * 128 * 4);
  int* rowptr = (int*)alloc((size_t)(N + 1) * 4);
  int* col    = (int*)alloc((size_t)Etot * 4);
  unsigned int* stg = (unsigned int*)alloc((size_t)Etot * 4);
  int* bcnt   = (int*)alloc(NBUK_MAX * 4);
  int* bbase  = (int*)alloc((NBUK_MAX + 1) * 4);
  int* bpos   = (int*)alloc(NBUK_MAX * 4);
  unsigned short* wt = (unsigned short*)alloc(16384 * 2);
  // layer-2 reuses dead layer-1 buffers
  float* h2p = (float*)h1s;   // N*40*4 B <= N*128*2 B
  float* as2 = as1;
  float* ad2 = ad1;

  hipMemsetAsync(bcnt, 0, NBUK_MAX * 4, stream);

  wtrans_k<<<64, 256, 0, stream>>>(W1, wt);
  gemm1_k<<<(N + 63) / 64, 256, 0, stream>>>(x, wt, att_s1, att_d1,
                                             h1s, as1, ad1, N);
  bhist_k<<<nchunk, 256, 0, stream>>>(ei, E, N, bcnt, nbuk);
  bscan_k<<<1, 256, 0, stream>>>(bcnt, bbase, bpos, nbuk);
  bscat_k<<<nchunk, 256, 0, stream>>>(ei, E, N, bpos, stg, nbuk);
  csr_k<<<nbuk, 512, 0, stream>>>(stg, bbase, rowptr, col, N, nbuk);

  agg1_k<<<(N + 3) / 4, 256, 0, stream>>>((const unsigned int*)h1s, as1, ad1,
                                          rowptr, col, b1,
                                          gamma, beta, mean, var, hmid, N);
  gemm2_k<<<(N + 127) / 128, 256, 0, stream>>>(hmid, W2, att_s2, att_d2,
                                               h2p, as2, ad2, N);
  agg2_k<<<(N + 3) / 4, 256, 0, stream>>>(h2p, as2, ad2, rowptr, col, b2,
                                          out, N);
}

// Round 11
// 167.373 us; speedup vs baseline: 1.2616x; 1.0668x over previous
//
#include <hip/hip_runtime.h>
#include <hip/hip_bf16.h>
#include <math.h>

#define LRELU(v) ((v) > 0.f ? (v) : 0.2f * (v))

typedef __attribute__((ext_vector_type(8))) short bf16x8;
typedef __attribute__((ext_vector_type(4))) float f32x4;

__device__ inline unsigned int f2bf(float f) {
  unsigned int u = __float_as_uint(f);
  return (u + 0x7fffu + ((u >> 16) & 1u)) >> 16;   // RNE
}
__device__ inline float bf_lo(unsigned int u) { return __uint_as_float(u << 16); }
__device__ inline float bf_hi(unsigned int u) { return __uint_as_float(u & 0xffff0000u); }

// ---- W1 transpose + bf16 convert: wt[c*128+k] = bf16(W1[k*128+c]) ---------
__global__ __launch_bounds__(256) void wtrans_k(const float* __restrict__ W,
                                                unsigned short* __restrict__ wt)
{
  int idx = blockIdx.x * 256 + threadIdx.x;   // 16384 elements
  int k = idx >> 7, c = idx & 127;
  wt[c * 128 + k] = (unsigned short)f2bf(W[idx]);
}

// ---- GEMM1 (MFMA bf16): h1 = x @ W1, fused a_s1/a_d1, h1 stored bf16 ------
#define LDA 152
__global__ __launch_bounds__(256) void gemm1_k(
    const float* __restrict__ x, const unsigned short* __restrict__ wt,
    const float* __restrict__ atts, const float* __restrict__ attd,
    unsigned short* __restrict__ h1s, float* __restrict__ as1,
    float* __restrict__ ad1, int N)
{
  __shared__ unsigned short xs[64 * LDA];
  const int t = threadIdx.x;
  const int row0 = blockIdx.x * 64;
  const int lane = t & 63, w = t >> 6;

#pragma unroll
  for (int i = 0; i < 8; ++i) {
    int idx = t + i * 256;
    int r = idx >> 5, kq = idx & 31;
    int rr = row0 + r;
    float4 v = make_float4(0.f, 0.f, 0.f, 0.f);
    if (rr < N) v = *reinterpret_cast<const float4*>(&x[(size_t)rr * 128 + kq * 4]);
    unsigned int p0 = f2bf(v.x) | (f2bf(v.y) << 16);
    unsigned int p1 = f2bf(v.z) | (f2bf(v.w) << 16);
    *reinterpret_cast<uint2*>(&xs[r * LDA + kq * 4]) = make_uint2(p0, p1);
  }
  __syncthreads();

  const int l16 = lane & 15, lhi = lane >> 4;
  const int nb0 = w * 32;
  f32x4 acc[4][2];
#pragma unroll
  for (int m = 0; m < 4; ++m)
#pragma unroll
    for (int n = 0; n < 2; ++n) acc[m][n] = (f32x4){0.f, 0.f, 0.f, 0.f};

#pragma unroll
  for (int ks = 0; ks < 4; ++ks) {
    bf16x8 bf[2];
#pragma unroll
    for (int n = 0; n < 2; ++n) {
      int col = nb0 + n * 16 + l16;
      bf[n] = *reinterpret_cast<const bf16x8*>(&wt[col * 128 + ks * 32 + 8 * lhi]);
    }
#pragma unroll
    for (int m = 0; m < 4; ++m) {
      bf16x8 af = *reinterpret_cast<const bf16x8*>(
          &xs[(m * 16 + l16) * LDA + ks * 32 + 8 * lhi]);
      acc[m][0] = __builtin_amdgcn_mfma_f32_16x16x32_bf16(af, bf[0], acc[m][0], 0, 0, 0);
      acc[m][1] = __builtin_amdgcn_mfma_f32_16x16x32_bf16(af, bf[1], acc[m][1], 0, 0, 0);
    }
  }

#pragma unroll
  for (int n = 0; n < 2; ++n) {
    int col = nb0 + n * 16 + l16;
    float av = atts[col], dv = attd[col];
    int head = w * 2 + n;
#pragma unroll
    for (int m = 0; m < 4; ++m) {
#pragma unroll
      for (int r = 0; r < 4; ++r) {
        int row = row0 + m * 16 + lhi * 4 + r;
        float v = acc[m][n][r];
        float s = v * av, d = v * dv;
        s += __shfl_xor(s, 1); s += __shfl_xor(s, 2);
        s += __shfl_xor(s, 4); s += __shfl_xor(s, 8);
        d += __shfl_xor(d, 1); d += __shfl_xor(d, 2);
        d += __shfl_xor(d, 4); d += __shfl_xor(d, 8);
        if (row < N) {
          h1s[(size_t)row * 128 + col] = (unsigned short)f2bf(v);
          if (l16 == 0) { as1[row * 8 + head] = s; ad1[row * 8 + head] = d; }
        }
      }
    }
  }
}

// ==== Binned CSR build =====================================================
#define NBUK_MAX 256

__global__ __launch_bounds__(256) void bhist_k(const int* __restrict__ ei,
                                               int E, int N,
                                               int* __restrict__ bcnt, int nbuk)
{
  __shared__ int h[NBUK_MAX];
  for (int i = threadIdx.x; i < nbuk; i += 256) h[i] = 0;
  __syncthreads();
  const int Etot = E + N;
  const int base = blockIdx.x * 4096;
#pragma unroll 4
  for (int i = threadIdx.x; i < 4096; i += 256) {
    int e = base + i;
    if (e < Etot) {
      int d = (e < E) ? ei[E + e] : (e - E);
      atomicAdd(&h[d >> 8], 1);
    }
  }
  __syncthreads();
  for (int i = threadIdx.x; i < nbuk; i += 256)
    if (h[i]) atomicAdd(&bcnt[i], h[i]);
}

__global__ __launch_bounds__(256) void bscan_k(const int* __restrict__ bcnt,
                                               int* __restrict__ bbase,
                                               int* __restrict__ bpos, int nbuk)
{
  __shared__ int wsum[4], wtot[4];
  const int t = threadIdx.x, lane = t & 63, w = t >> 6;
  int v = (t < nbuk) ? bcnt[t] : 0;
  int incl = v;
#pragma unroll
  for (int off = 1; off < 64; off <<= 1) {
    int y = __shfl_up(incl, off);
    if (lane >= off) incl += y;
  }
  if (lane == 63) wtot[w] = incl;
  __syncthreads();
  if (t == 0) {
    int a = wtot[0], b = wtot[1], c = wtot[2];
    wsum[0] = 0; wsum[1] = a; wsum[2] = a + b; wsum[3] = a + b + c;
  }
  __syncthreads();
  int ex = wsum[w] + incl - v;
  if (t < nbuk) { bbase[t] = ex; bpos[t] = ex; }
  if (t == nbuk - 1) bbase[nbuk] = ex + v;
}

__global__ __launch_bounds__(256) void bscat_k(const int* __restrict__ ei,
                                               int E, int N,
                                               int* __restrict__ bpos,
                                               unsigned int* __restrict__ stg,
                                               int nbuk)
{
  __shared__ int h[NBUK_MAX], gp[NBUK_MAX], cur[NBUK_MAX];
  for (int i = threadIdx.x; i < nbuk; i += 256) { h[i] = 0; cur[i] = 0; }
  __syncthreads();
  const int Etot = E + N;
  const int base = blockIdx.x * 4096;
  int s[16], d[16];
#pragma unroll
  for (int i = 0; i < 16; ++i) {
    int e = base + i * 256 + threadIdx.x;
    if (e < Etot) {
      if (e < E) { s[i] = ei[e]; d[i] = ei[E + e]; }
      else       { s[i] = d[i] = e - E; }
      atomicAdd(&h[d[i] >> 8], 1);
    } else d[i] = -1;
  }
  __syncthreads();
  for (int i = threadIdx.x; i < nbuk; i += 256)
    gp[i] = h[i] ? atomicAdd(&bpos[i], h[i]) : 0;
  __syncthreads();
#pragma unroll
  for (int i = 0; i < 16; ++i) {
    if (d[i] >= 0) {
      int b = d[i] >> 8;
      int r = atomicAdd(&cur[b], 1);
      stg[gp[b] + r] = ((unsigned int)s[i] << 8) | (unsigned int)(d[i] & 255);
    }
  }
}

#define CCAP 4992
__global__ __launch_bounds__(512) void csr_k(const unsigned int* __restrict__ stg,
                                             const int* __restrict__ bbase,
                                             int* __restrict__ rowptr,
                                             int* __restrict__ col,
                                             int N, int nbuk)
{
  __shared__ int nh[256], nb[257], cur[256], wsum[4];
  __shared__ int cstage[CCAP];
  const int b = blockIdx.x, t = threadIdx.x;
  const int n0 = b << 8;
  const int e0 = bbase[b], e1 = bbase[b + 1], cnt = e1 - e0;
  if (t < 256) { nh[t] = 0; cur[t] = 0; }
  __syncthreads();
  for (int i = t; i < cnt; i += 512)
    atomicAdd(&nh[stg[e0 + i] & 255u], 1);
  __syncthreads();
  if (t < 256) {
    const int lane = t & 63, w = t >> 6;
    int v = nh[t], incl = v;
#pragma unroll
    for (int off = 1; off < 64; off <<= 1) {
      int y = __shfl_up(incl, off);
      if (lane >= off) incl += y;
    }
    if (lane == 63) wsum[w] = incl;
    __syncthreads();
    if (t == 0) {
      int a = wsum[0], bb = wsum[1], c = wsum[2];
      wsum[0] = 0; wsum[1] = a; wsum[2] = a + bb; wsum[3] = a + bb + c;
    }
    __syncthreads();
    int ex = wsum[w] + incl - v;
    nb[t] = ex;
    if (t == 255) nb[256] = ex + v;
  } else {
    __syncthreads();
    __syncthreads();
  }
  __syncthreads();
  const int nnodes = min(256, N - n0);
  for (int i = t; i < nnodes; i += 512) rowptr[n0 + i] = e0 + nb[i];
  if (b == nbuk - 1 && t == 0) rowptr[N] = e1;
  for (int i = t; i < cnt; i += 512) {
    unsigned int sd = stg[e0 + i];
    int li = sd & 255u;
    int p = nb[li] + atomicAdd(&cur[li], 1);
    int sv = (int)(sd >> 8);
    if (p < CCAP) cstage[p] = sv; else col[e0 + p] = sv;
  }
  __syncthreads();
  const int lim = min(cnt, CCAP);
  for (int i = t; i < lim; i += 512) col[e0 + i] = cstage[i];
}

// ---- AGG1: 2 edges/step x 32 lanes (4ch via uint2), 4 steps/iter ----------
__global__ __launch_bounds__(256) void agg1_k(
    const unsigned int* __restrict__ h1b, const float* __restrict__ as1,
    const float* __restrict__ ad1, const int* __restrict__ rowptr,
    const int* __restrict__ col, const float* __restrict__ b1,
    const float* __restrict__ gamma, const float* __restrict__ beta,
    const float* __restrict__ mean, const float* __restrict__ var,
    float* __restrict__ hmid, int N)
{
  const int wid = threadIdx.x >> 6, lane = threadIdx.x & 63;
  const int n = blockIdx.x * 4 + wid;
  if (n >= N) return;
  const int eh = lane >> 5;          // which edge of the pair
  const int cl = lane & 31;          // channel quad: ch 4cl..4cl+3
  const int h  = cl >> 2;            // head
  const float adv = ad1[n * 8 + h];
  float den = 0.f, a0 = 0.f, a1 = 0.f, a2 = 0.f, a3 = 0.f;
  const int jb = rowptr[n], je = rowptr[n + 1];
  for (int j = jb; j < je; j += 8) {
    int s[4]; bool v[4];
#pragma unroll
    for (int q = 0; q < 4; ++q) {
      int idx = j + 2 * q + eh;
      v[q] = idx < je;
      s[q] = col[v[q] ? idx : je - 1];
    }
    float e[4];
#pragma unroll
    for (int q = 0; q < 4; ++q) e[q] = as1[s[q] * 8 + h];
    uint2 u[4];
#pragma unroll
    for (int q = 0; q < 4; ++q)
      u[q] = *reinterpret_cast<const uint2*>(&h1b[s[q] * 64 + cl * 2]);
#pragma unroll
    for (int q = 0; q < 4; ++q) {
      float p = v[q] ? __expf(LRELU(e[q] + adv)) : 0.f;
      den += p;
      a0 += p * bf_lo(u[q].x);
      a1 += p * bf_hi(u[q].x);
      a2 += p * bf_lo(u[q].y);
      a3 += p * bf_hi(u[q].y);
    }
  }
  den += __shfl_xor(den, 32);
  a0 += __shfl_xor(a0, 32);
  a1 += __shfl_xor(a1, 32);
  a2 += __shfl_xor(a2, 32);
  a3 += __shfl_xor(a3, 32);
  if (eh == 0) {
    const int c0 = cl * 4;
    float r = 1.f / (den + 1e-16f);
    float4 bb = *reinterpret_cast<const float4*>(&b1[c0]);
    float4 mm = *reinterpret_cast<const float4*>(&mean[c0]);
    float4 vv = *reinterpret_cast<const float4*>(&var[c0]);
    float4 gg = *reinterpret_cast<const float4*>(&gamma[c0]);
    float4 be = *reinterpret_cast<const float4*>(&beta[c0]);
    float o0 = a0 * r + bb.x, o1 = a1 * r + bb.y;
    float o2 = a2 * r + bb.z, o3 = a3 * r + bb.w;
    float n0 = (o0 - mm.x) * rsqrtf(vv.x + 1e-5f) * gg.x + be.x;
    float n1 = (o1 - mm.y) * rsqrtf(vv.y + 1e-5f) * gg.y + be.y;
    float n2 = (o2 - mm.z) * rsqrtf(vv.z + 1e-5f) * gg.z + be.z;
    float n3 = (o3 - mm.w) * rsqrtf(vv.w + 1e-5f) * gg.w + be.w;
    float4 o;
    o.x = n0 > 0.f ? n0 : expm1f(n0);
    o.y = n1 > 0.f ? n1 : expm1f(n1);
    o.z = n2 > 0.f ? n2 : expm1f(n2);
    o.w = n3 > 0.f ? n3 : expm1f(n3);
    *reinterpret_cast<float4*>(&hmid[n * 128 + c0]) = o;
  }
}

// ---- GEMM2: h2p = hmid @ W2 (128->40) f32, fused a_s2/a_d2 ----------------
__global__ __launch_bounds__(256) void gemm2_k(
    const float* __restrict__ hmid, const float* __restrict__ W2,
    const float* __restrict__ atts, const float* __restrict__ attd,
    float* __restrict__ h2p, float* __restrict__ as2, float* __restrict__ ad2,
    int N)
{
  __shared__ float hm[128 * 36];
  __shared__ float w2t[40 * 36];
  const int t = threadIdx.x;
  const int n0 = blockIdx.x * 128;
  const int lane = t & 63, w = t >> 6;
  const int ng = lane >> 3, cg = lane & 7;
  const int nloc = w * 32 + ng * 4;

  float acc[4][5];
#pragma unroll
  for (int i = 0; i < 4; ++i)
#pragma unroll
    for (int j = 0; j < 5; ++j) acc[i][j] = 0.f;

  for (int kc = 0; kc < 4; ++kc) {
    __syncthreads();
#pragma unroll
    for (int i = 0; i < 4; ++i) {
      int idx = t + i * 256;
      int r = idx >> 3, kq = idx & 7;
      int rr = n0 + r;
      float4 v = make_float4(0.f, 0.f, 0.f, 0.f);
      if (rr < N)
        v = *reinterpret_cast<const float4*>(&hmid[(size_t)rr * 128 + kc * 32 + kq * 4]);
      *reinterpret_cast<float4*>(&hm[r * 36 + kq * 4]) = v;
    }
#pragma unroll
    for (int i = 0; i < 5; ++i) {
      int flat = t + i * 256;
      int c = flat >> 5, kk = flat & 31;
      w2t[c * 36 + kk] = W2[(size_t)(kc * 32 + kk) * 40 + c];
    }
    __syncthreads();
#pragma unroll
    for (int k4 = 0; k4 < 8; ++k4) {
      float hv[4][4];
#pragma unroll
      for (int i = 0; i < 4; ++i)
        *reinterpret_cast<float4*>(hv[i]) =
            *reinterpret_cast<const float4*>(&hm[(nloc + i) * 36 + k4 * 4]);
      float wv[5][4];
#pragma unroll
      for (int j = 0; j < 5; ++j)
        *reinterpret_cast<float4*>(wv[j]) =
            *reinterpret_cast<const float4*>(&w2t[(cg * 5 + j) * 36 + k4 * 4]);
#pragma unroll
      for (int i = 0; i < 4; ++i)
#pragma unroll
        for (int j = 0; j < 5; ++j)
#pragma unroll
          for (int kk = 0; kk < 4; ++kk)
            acc[i][j] += hv[i][kk] * wv[j][kk];
    }
  }

  float asv[5], adv[5];
#pragma unroll
  for (int j = 0; j < 5; ++j) { asv[j] = atts[cg * 5 + j]; adv[j] = attd[cg * 5 + j]; }
#pragma unroll
  for (int i = 0; i < 4; ++i) {
    int n = n0 + nloc + i;
    if (n >= N) continue;
    float ps = 0.f, pd = 0.f;
#pragma unroll
    for (int j = 0; j < 5; ++j) { ps += acc[i][j] * asv[j]; pd += acc[i][j] * adv[j]; }
#pragma unroll
    for (int off = 1; off < 8; off <<= 1) {
      ps += __shfl_xor(ps, off);
      pd += __shfl_xor(pd, off);
    }
#pragma unroll
    for (int j = 0; j < 5; ++j) h2p[(size_t)n * 40 + cg * 5 + j] = acc[i][j];
    if (cg == 0) { as2[n] = ps; ad2[n] = pd; }
  }
}

// ---- AGG2: 2 edges/step x 32 lanes (2ch via float2), 4 steps/iter ---------
__global__ __launch_bounds__(256) void agg2_k(
    const float* __restrict__ h2p, const float* __restrict__ as2,
    const float* __restrict__ ad2, const int* __restrict__ rowptr,
    const int* __restrict__ col, const float* __restrict__ b2,
    float* __restrict__ out, int N)
{
  const int wid = threadIdx.x >> 6, lane = threadIdx.x & 63;
  const int n = blockIdx.x * 4 + wid;
  if (n >= N) return;
  const int eh = lane >> 5;
  const int cl = lane & 31;          // channel pair 2cl,2cl+1 (cl<20 active)
  const bool actc = cl < 20;
  const int c0 = (actc ? cl : 19) * 2;
  const float adv = ad2[n];
  float den = 0.f, a0 = 0.f, a1 = 0.f;
  const int jb = rowptr[n], je = rowptr[n + 1];
  for (int j = jb; j < je; j += 8) {
    int s[4]; bool v[4];
#pragma unroll
    for (int q = 0; q < 4; ++q) {
      int idx = j + 2 * q + eh;
      v[q] = idx < je;
      s[q] = col[v[q] ? idx : je - 1];
    }
    float e[4];
#pragma unroll
    for (int q = 0; q < 4; ++q) e[q] = as2[s[q]];
    float2 f[4];
#pragma unroll
    for (int q = 0; q < 4; ++q)
      f[q] = *reinterpret_cast<const float2*>(&h2p[s[q] * 40 + c0]);
#pragma unroll
    for (int q = 0; q < 4; ++q) {
      float p = v[q] ? __expf(LRELU(e[q] + adv)) : 0.f;
      den += p;
      a0 += p * f[q].x;
      a1 += p * f[q].y;
    }
  }
  den += __shfl_xor(den, 32);
  a0 += __shfl_xor(a0, 32);
  a1 += __shfl_xor(a1, 32);
  // lanes 0-31 finish: bias + row log_softmax over 20 lanes x 2 values
  float r = 1.f / (den + 1e-16f);
  float o0 = a0 * r + b2[c0];
  float o1 = a1 * r + b2[c0 + 1];
  const bool act = actc && (eh == 0);
  float mv = act ? fmaxf(o0, o1) : -INFINITY;
#pragma unroll
  for (int off = 1; off < 32; off <<= 1) mv = fmaxf(mv, __shfl_xor(mv, off));
  float ex = act ? (__expf(o0 - mv) + __expf(o1 - mv)) : 0.f;
#pragma unroll
  for (int off = 1; off < 32; off <<= 1) ex += __shfl_xor(ex, off);
  float ls = logf(ex);
  if (act) {
    float2 ov = make_float2(o0 - mv - ls, o1 - mv - ls);
    *reinterpret_cast<float2*>(&out[n * 40 + c0]) = ov;
  }
}

// ---------------------------------------------------------------------------
extern "C" void kernel_launch(void* const* d_in, const int* in_sizes, int n_in,
                              void* d_out, int out_size, void* d_ws,
                              size_t ws_size, hipStream_t stream)
{
  const float* x      = (const float*)d_in[0];
  const int*   ei     = (const int*)d_in[1];
  const float* W1     = (const float*)d_in[2];
  const float* att_s1 = (const float*)d_in[3];
  const float* att_d1 = (const float*)d_in[4];
  const float* b1     = (const float*)d_in[5];
  const float* gamma  = (const float*)d_in[6];
  const float* beta   = (const float*)d_in[7];
  const float* mean   = (const float*)d_in[8];
  const float* var    = (const float*)d_in[9];
  const float* W2     = (const float*)d_in[10];
  const float* att_s2 = (const float*)d_in[11];
  const float* att_d2 = (const float*)d_in[12];
  const float* b2     = (const float*)d_in[13];
  float* out = (float*)d_out;

  const int N = in_sizes[0] / 128;
  const int E = in_sizes[1] / 2;
  const int Etot = E + N;
  const int nbuk = (N + 255) >> 8;
  const int nchunk = (Etot + 4095) / 4096;

  char* ws = (char*)d_ws;
  size_t off = 0;
  auto alloc = [&](size_t bytes) -> void* {
    void* p = ws + off;
    off = (off + bytes + 255) & ~(size_t)255;
    return p;
  };
  unsigned short* h1s = (unsigned short*)alloc((size_t)N * 128 * 2);
  float* as1  = (float*)alloc((size_t)N * 8 * 4);
  float* ad1  = (float*)alloc((size_t)N * 8 * 4);
  float* hmid = (float*)alloc((size_t)N * 128 * 4);
  int* rowptr = (int*)alloc((size_t)(N + 1) * 4);
  int* col    = (int*)alloc((size_t)Etot * 4);
  unsigned int* stg = (unsigned int*)alloc((size_t)Etot * 4);
  int* bcnt   = (int*)alloc(NBUK_MAX * 4);
  int* bbase  = (int*)alloc((NBUK_MAX + 1) * 4);
  int* bpos   = (int*)alloc(NBUK_MAX * 4);
  unsigned short* wt = (unsigned short*)alloc(16384 * 2);
  // layer-2 reuses dead layer-1 buffers
  float* h2p = (float*)h1s;   // N*40*4 B <= N*128*2 B
  float* as2 = as1;
  float* ad2 = ad1;

  hipMemsetAsync(bcnt, 0, NBUK_MAX * 4, stream);

  wtrans_k<<<64, 256, 0, stream>>>(W1, wt);
  gemm1_k<<<(N + 63) / 64, 256, 0, stream>>>(x, wt, att_s1, att_d1,
                                             h1s, as1, ad1, N);
  bhist_k<<<nchunk, 256, 0, stream>>>(ei, E, N, bcnt, nbuk);
  bscan_k<<<1, 256, 0, stream>>>(bcnt, bbase, bpos, nbuk);
  bscat_k<<<nchunk, 256, 0, stream>>>(ei, E, N, bpos, stg, nbuk);
  csr_k<<<nbuk, 512, 0, stream>>>(stg, bbase, rowptr, col, N, nbuk);

  agg1_k<<<(N + 3) / 4, 256, 0, stream>>>((const unsigned int*)h1s, as1, ad1,
                                          rowptr, col, b1,
                                          gamma, beta, mean, var, hmid, N);
  gemm2_k<<<(N + 127) / 128, 256, 0, stream>>>(hmid, W2, att_s2, att_d2,
                                               h2p, as2, ad2, N);
  agg2_k<<<(N + 3) / 4, 256, 0, stream>>>(h2p, as2, ad2, rowptr, col, b2,
                                          out, N);
}